// Round 1
// baseline (204.916 us; speedup 1.0000x reference)
//
#include <hip/hip_runtime.h>

// AnchorLoss: sum over (b,i,j) of mask[b,i,j]==1 ? 1-exp(-||p_i-p_j||^2/T) : 0
// where p = embedding + abs_coords, shape [B,N,2]. Output: single fp32 scalar.
//
// B=8, N=2048, D=2. mask is int32 [B,N,N] = 134 MB -> memory-bound (~21us floor).

constexpr int B_ = 8;
constexpr int N_ = 2048;
constexpr int ROWS = 16;       // i-rows per block
constexpr int THREADS = 256;
constexpr float INV_TEMP = 0.1f;   // 1/10.0

__global__ void zero_out_kernel(float* out) { out[0] = 0.0f; }

__global__ __launch_bounds__(THREADS)
void anchor_loss_kernel(const float* __restrict__ emb,
                        const float* __restrict__ coords,
                        const int*   __restrict__ mask,
                        float* __restrict__ out)
{
    // SoA staging of p = emb + coords for this block's batch.
    // SoA => lane t reads float4 px[4t..4t+3] : consecutive 16B across lanes,
    // conflict-free ds_read_b128.
    __shared__ __align__(16) float px[N_];
    __shared__ __align__(16) float py[N_];
    __shared__ float wave_sum[THREADS / 64];

    const int blk = blockIdx.x;
    const int b   = blk / (N_ / ROWS);
    const int i0  = (blk % (N_ / ROWS)) * ROWS;
    const int t   = threadIdx.x;

    const float* eb = emb    + (size_t)b * N_ * 2;
    const float* cb = coords + (size_t)b * N_ * 2;

    // 2048 points * 2 floats = 4096 floats; float4 = 2 points per load.
    for (int k = t; k < N_ / 2; k += THREADS) {
        float4 e = reinterpret_cast<const float4*>(eb)[k];
        float4 c = reinterpret_cast<const float4*>(cb)[k];
        px[2 * k]     = e.x + c.x;
        py[2 * k]     = e.y + c.y;
        px[2 * k + 1] = e.z + c.z;
        py[2 * k + 1] = e.w + c.w;
    }
    __syncthreads();

    float acc = 0.0f;

    for (int r = 0; r < ROWS; ++r) {
        const int i = i0 + r;
        const float pix = px[i];   // same-address broadcast: free
        const float piy = py[i];
        const int4* mrow =
            reinterpret_cast<const int4*>(mask + ((size_t)b * N_ + i) * N_);

        #pragma unroll
        for (int s = 0; s < N_ / (4 * THREADS); ++s) {
            const int j4 = t + s * THREADS;           // int4 index; coalesced
            const int4  m  = mrow[j4];
            const float4 qx = reinterpret_cast<const float4*>(px)[j4];
            const float4 qy = reinterpret_cast<const float4*>(py)[j4];

            float dx, dy, d2;
            dx = pix - qx.x; dy = piy - qy.x; d2 = dx * dx + dy * dy;
            acc += (m.x == 1) ? (1.0f - __expf(-d2 * INV_TEMP)) : 0.0f;
            dx = pix - qx.y; dy = piy - qy.y; d2 = dx * dx + dy * dy;
            acc += (m.y == 1) ? (1.0f - __expf(-d2 * INV_TEMP)) : 0.0f;
            dx = pix - qx.z; dy = piy - qy.z; d2 = dx * dx + dy * dy;
            acc += (m.z == 1) ? (1.0f - __expf(-d2 * INV_TEMP)) : 0.0f;
            dx = pix - qx.w; dy = piy - qy.w; d2 = dx * dx + dy * dy;
            acc += (m.w == 1) ? (1.0f - __expf(-d2 * INV_TEMP)) : 0.0f;
        }
    }

    // Wave (64-lane) shuffle reduction.
    #pragma unroll
    for (int o = 32; o > 0; o >>= 1) acc += __shfl_down(acc, o);

    if ((t & 63) == 0) wave_sum[t >> 6] = acc;
    __syncthreads();
    if (t == 0) {
        float s = 0.0f;
        #pragma unroll
        for (int w = 0; w < THREADS / 64; ++w) s += wave_sum[w];
        atomicAdd(out, s);   // device-scope by default; 1024 blocks total
    }
}

extern "C" void kernel_launch(void* const* d_in, const int* in_sizes, int n_in,
                              void* d_out, int out_size, void* d_ws, size_t ws_size,
                              hipStream_t stream) {
    const float* emb    = (const float*)d_in[0];
    const float* coords = (const float*)d_in[1];
    const int*   mask   = (const int*)d_in[2];
    float* out = (float*)d_out;

    // d_out is poisoned with 0xAA before every timed launch -> zero it first.
    zero_out_kernel<<<1, 1, 0, stream>>>(out);

    const int grid = B_ * (N_ / ROWS);   // 1024 blocks
    anchor_loss_kernel<<<grid, THREADS, 0, stream>>>(emb, coords, mask, out);
}

// Round 3
// 203.210 us; speedup vs baseline: 1.0084x; 1.0084x over previous
//
#include <hip/hip_runtime.h>

// AnchorLoss: sum over (b,i,j) of mask[b,i,j]==1 ? 1-exp(-||p_i-p_j||^2/T) : 0
// where p = embedding + abs_coords, shape [B,N,2]. Output: single fp32 scalar.
//
// B=8, N=2048, D=2. mask int32 [B,N,N] = 134 MB streamed once -> memory-bound,
// floor ~21us @ 6.3 TB/s. Points (256 KB) staged in LDS as SoA.

constexpr int B_ = 8;
constexpr int N_ = 2048;
constexpr int ROWS = 8;        // i-rows per block -> 2048 blocks, 8/CU
constexpr int THREADS = 256;
constexpr float INV_TEMP = 0.1f;   // 1/10.0

// Native clang vector type: required by __builtin_nontemporal_load
// (HIP_vector_type<int,4> is a struct and is rejected).
typedef int ivec4 __attribute__((ext_vector_type(4)));

__global__ void zero_out_kernel(float* out) { out[0] = 0.0f; }

__global__ __launch_bounds__(THREADS)
void anchor_loss_kernel(const float* __restrict__ emb,
                        const float* __restrict__ coords,
                        const int*   __restrict__ mask,
                        float* __restrict__ out)
{
    // SoA staging of p = emb + coords: lane t reads float4 px[4t..4t+3],
    // consecutive 16B across lanes -> conflict-free ds_read_b128.
    __shared__ __align__(16) float px[N_];
    __shared__ __align__(16) float py[N_];
    __shared__ float wave_sum[THREADS / 64];

    const int blk = blockIdx.x;
    const int b   = blk / (N_ / ROWS);
    const int i0  = (blk % (N_ / ROWS)) * ROWS;
    const int t   = threadIdx.x;

    const float* eb = emb    + (size_t)b * N_ * 2;
    const float* cb = coords + (size_t)b * N_ * 2;

    for (int k = t; k < N_ / 2; k += THREADS) {
        float4 e = reinterpret_cast<const float4*>(eb)[k];
        float4 c = reinterpret_cast<const float4*>(cb)[k];
        px[2 * k]     = e.x + c.x;
        py[2 * k]     = e.y + c.y;
        px[2 * k + 1] = e.z + c.z;
        py[2 * k + 1] = e.w + c.w;
    }
    __syncthreads();

    const ivec4* mbase =
        reinterpret_cast<const ivec4*>(mask + ((size_t)b * N_ + i0) * N_);
    constexpr int ROW4 = N_ / 4;          // ivec4 per mask row

    float acc = 0.0f;

    // Double-buffered non-temporal mask loads: next row's two 16B loads are
    // in flight while the current row's exp chain executes.
    ivec4 m0 = __builtin_nontemporal_load(mbase + t);
    ivec4 m1 = __builtin_nontemporal_load(mbase + t + THREADS);

    for (int r = 0; r < ROWS; ++r) {
        ivec4 n0 = {0, 0, 0, 0}, n1 = {0, 0, 0, 0};
        if (r + 1 < ROWS) {
            const ivec4* mnext = mbase + (size_t)(r + 1) * ROW4;
            n0 = __builtin_nontemporal_load(mnext + t);
            n1 = __builtin_nontemporal_load(mnext + t + THREADS);
        }

        const int i = i0 + r;
        const float pix = px[i];   // same-address LDS broadcast: free
        const float piy = py[i];

        #pragma unroll
        for (int s = 0; s < 2; ++s) {
            const ivec4  m  = (s == 0) ? m0 : m1;
            const int    j4 = t + s * THREADS;
            const float4 qx = reinterpret_cast<const float4*>(px)[j4];
            const float4 qy = reinterpret_cast<const float4*>(py)[j4];

            float dx, dy, d2;
            dx = pix - qx.x; dy = piy - qy.x; d2 = dx * dx + dy * dy;
            acc += (m.x == 1) ? (1.0f - __expf(-d2 * INV_TEMP)) : 0.0f;
            dx = pix - qx.y; dy = piy - qy.y; d2 = dx * dx + dy * dy;
            acc += (m.y == 1) ? (1.0f - __expf(-d2 * INV_TEMP)) : 0.0f;
            dx = pix - qx.z; dy = piy - qy.z; d2 = dx * dx + dy * dy;
            acc += (m.z == 1) ? (1.0f - __expf(-d2 * INV_TEMP)) : 0.0f;
            dx = pix - qx.w; dy = piy - qy.w; d2 = dx * dx + dy * dy;
            acc += (m.w == 1) ? (1.0f - __expf(-d2 * INV_TEMP)) : 0.0f;
        }

        m0 = n0; m1 = n1;
    }

    // Wave (64-lane) shuffle reduction.
    #pragma unroll
    for (int o = 32; o > 0; o >>= 1) acc += __shfl_down(acc, o);

    if ((t & 63) == 0) wave_sum[t >> 6] = acc;
    __syncthreads();
    if (t == 0) {
        float s = 0.0f;
        #pragma unroll
        for (int w = 0; w < THREADS / 64; ++w) s += wave_sum[w];
        atomicAdd(out, s);   // 2048 atomics total, negligible
    }
}

extern "C" void kernel_launch(void* const* d_in, const int* in_sizes, int n_in,
                              void* d_out, int out_size, void* d_ws, size_t ws_size,
                              hipStream_t stream) {
    const float* emb    = (const float*)d_in[0];
    const float* coords = (const float*)d_in[1];
    const int*   mask   = (const int*)d_in[2];
    float* out = (float*)d_out;

    // d_out is poisoned with 0xAA before every timed launch -> zero it first.
    zero_out_kernel<<<1, 1, 0, stream>>>(out);

    const int grid = B_ * (N_ / ROWS);   // 2048 blocks
    anchor_loss_kernel<<<grid, THREADS, 0, stream>>>(emb, coords, mask, out);
}